// Round 4
// baseline (413.936 us; speedup 1.0000x reference)
//
#include <hip/hip_runtime.h>
#include <hip/hip_bf16.h>
#include <hip/hip_cooperative_groups.h>

namespace cg = cooperative_groups;

// Problem constants
constexpr int cB = 4;
constexpr int cN = 4096;
constexpr int cD = 512;
constexpr int cK = 64;
constexpr int cNB = cB * cN;       // 16384 rows
constexpr int cNP = cN + 1;        // 4097 prefix rows
constexpr int cCS = 16;            // chunk size for scans
constexpr int cNC = cN / cCS;      // 256 chunks per batch
constexpr int cNC1 = cNC + 1;      // 257

typedef unsigned short u16;
typedef unsigned int u32;
typedef unsigned long long u64;
typedef __bf16 bf16x8 __attribute__((ext_vector_type(8)));
typedef float f32x4 __attribute__((ext_vector_type(4)));

// ---- workspace layout (in floats) ----
constexpr size_t OFF_H    = 0;                                  // cNB*cK
constexpr size_t OFF_T1   = OFF_H    + (size_t)cNB * cK;        // cNB
constexpr size_t OFF_T2   = OFF_T1   + cNB;                     // cNB
constexpr size_t OFF_T2S  = OFF_T2   + cNB;                     // cNB (sorted)
constexpr size_t OFF_IDX  = OFF_T2S  + cNB;                     // cNB (int)
constexpr size_t OFF_P    = OFF_IDX  + cNB;                     // cNB (int) split point per row
constexpr size_t OFF_EPL  = OFF_P    + cNB;                     // cB*cNP*cK
constexpr size_t OFF_GNL  = OFF_EPL  + (size_t)cB * cNP * cK;   // cB*cNP*cK
constexpr size_t OFF_EPS  = OFF_GNL  + (size_t)cB * cNP * cK;   // cB*cNP
constexpr size_t OFF_GNS  = OFF_EPS  + (size_t)cB * cNP;        // cB*cNP
constexpr size_t OFF_CHE  = OFF_GNS  + (size_t)cB * cNP;        // cB*cNC*cK
constexpr size_t OFF_CHG  = OFF_CHE  + (size_t)cB * cNC * cK;
constexpr size_t OFF_CHES = OFF_CHG  + (size_t)cB * cNC * cK;   // cB*cNC
constexpr size_t OFF_CHGS = OFF_CHES + (size_t)cB * cNC;
constexpr size_t OFF_OFE  = OFF_CHGS + (size_t)cB * cNC;        // cB*cNC1*cK
constexpr size_t OFF_OFG  = OFF_OFE  + (size_t)cB * cNC1 * cK;
constexpr size_t OFF_OFES = OFF_OFG  + (size_t)cB * cNC1 * cK;  // cB*cNC1
constexpr size_t OFF_OFGS = OFF_OFES + (size_t)cB * cNC1;
constexpr size_t OFF_XB16 = OFF_OFGS + (size_t)cB * cNC1;       // cNB*cD u16 (fallback path only)
constexpr size_t OFF_WB16 = OFF_XB16 + (size_t)cNB * cD / 2;    // cK*cD u16

__device__ __forceinline__ u16 f2bf(float f) {
    unsigned u = __float_as_uint(f);
    u += 0x7fffu + ((u >> 16) & 1u);   // RNE
    return (u16)(u >> 16);
}
__device__ __forceinline__ u32 pk2(float a, float b) {
    return (u32)f2bf(a) | ((u32)f2bf(b) << 16);
}
// monotone float -> sortable uint (ascending)
__device__ __forceinline__ u32 f2sort(float f) {
    u32 b = __float_as_uint(f);
    u32 mask = (u32)((int)b >> 31);
    return b ^ (mask | 0x80000000u);
}

// ===========================================================================
// MEGA-KERNEL (cooperative): 256 blocks x 512 threads, 100 KB dynamic LDS.
// Block owns 64 output rows. LDS A-tile (bf16, XOR-swizzled) persists from
// P1 staging through P3 MFMA -> x is read from HBM exactly once, no xb16.
// Grid syncs replace 4 kernel boundaries.
//   P0: fold Wa*Wb/Wc -> wabL/wacL (LDS); blocks 0-15 emit wab16 (bf16 B).
//   P1: x tile -> lds_a + exact f32 t1/t2.               [grid sync]
//   P2: rank + split-point (LDS keys, fused pidx).
//   P3: GEMM h = A(lds) x B(wab16, L2).                  [grid sync]
//   P4: chunkscan, 4 chunks/block, E-wave/G-wave split.  [grid sync]
//   P5: offsets (blocks 0-7).                            [grid sync]
//   P6: out, 64 rows/block.
// LDS map: [0,64K) A-tile | [64K,96K) keys (overlaid by wabL/wacL in P0/P1)
//          | [96K,100K) part/wsum.
// ===========================================================================
__global__ __launch_bounds__(512, 1) void k_mega(
    const float* __restrict__ x, const float* __restrict__ Wa,
    const float* __restrict__ Wb, const float* __restrict__ wbb,
    const float* __restrict__ Wc, const float* __restrict__ wcb,
    const float* __restrict__ bias, float* __restrict__ out,
    float* __restrict__ t1, float* __restrict__ t2,
    float* __restrict__ t2s, int* __restrict__ idxs, int* __restrict__ pidx,
    u16* __restrict__ wab16, float* __restrict__ h,
    float* __restrict__ EpL, float* __restrict__ GnL,
    float* __restrict__ eps_l, float* __restrict__ gns_l,
    float* __restrict__ chE, float* __restrict__ chG,
    float* __restrict__ chEs, float* __restrict__ chGs,
    float* __restrict__ ofE, float* __restrict__ ofG,
    float* __restrict__ ofEs, float* __restrict__ ofGs)
{
    extern __shared__ char smem[];
    cg::grid_group grid = cg::this_grid();
    int t = threadIdx.x;
    int blk = blockIdx.x;
    float* wabL = (float*)(smem + 65536);
    float* wacL = wabL + cD;

    // ---- P0: fold vectors + wab16 emit ----
    {
        float s1 = 0.f, s2 = 0.f;
#pragma unroll 8
        for (int k = 0; k < cK; ++k) {
            float w = Wa[k * cD + t];
            s1 += w * Wb[k];
            s2 += w * Wc[k];
        }
        wabL[t] = s1; wacL[t] = s2;
        if (blk < 16) {                      // 16 blocks x 512 thr x 4 = 32768 = cK*cD
            int i4 = (blk * 512 + t) * 4;
            float4 v = *(const float4*)(Wa + i4);
            uint2 p = {pk2(v.x, v.y), pk2(v.z, v.w)};
            *(uint2*)(wab16 + i4) = p;
        }
    }
    __syncthreads();

    // ---- P1: stage x tile (bf16, swizzled) + exact f32 t1/t2 ----
    {
        int row = t >> 3, s8 = t & 7;        // 8 threads per row
        int rowg = blk * 64 + row;
        const float* xr = x + (size_t)rowg * cD;
        float p1 = 0.f, p2 = 0.f;
        char* arow = smem + row * 1024;
        unsigned swz = (unsigned)(row & 7) << 4;
#pragma unroll
        for (int i = 0; i < 8; ++i) {
            int col = i * 64 + s8 * 8;       // 8 lanes cover 64 consecutive cols
            float4 a  = *(const float4*)(xr + col);
            float4 b  = *(const float4*)(xr + col + 4);
            float4 wa1 = *(const float4*)(wabL + col);
            float4 wa2 = *(const float4*)(wabL + col + 4);
            float4 wc1 = *(const float4*)(wacL + col);
            float4 wc2 = *(const float4*)(wacL + col + 4);
            p1 += a.x*wa1.x + a.y*wa1.y + a.z*wa1.z + a.w*wa1.w
                + b.x*wa2.x + b.y*wa2.y + b.z*wa2.z + b.w*wa2.w;
            p2 += a.x*wc1.x + a.y*wc1.y + a.z*wc1.z + a.w*wc1.w
                + b.x*wc2.x + b.y*wc2.y + b.z*wc2.z + b.w*wc2.w;
            uint4 pk = {pk2(a.x, a.y), pk2(a.z, a.w), pk2(b.x, b.y), pk2(b.z, b.w)};
            *(uint4*)(arow + (((unsigned)(col * 2)) ^ swz)) = pk;
        }
        p1 += __shfl_xor(p1, 1, 64); p1 += __shfl_xor(p1, 2, 64); p1 += __shfl_xor(p1, 4, 64);
        p2 += __shfl_xor(p2, 1, 64); p2 += __shfl_xor(p2, 2, 64); p2 += __shfl_xor(p2, 4, 64);
        if (s8 == 0) { t1[rowg] = p1 + wbb[0]; t2[rowg] = p2 + wcb[0]; }
    }
    __threadfence();
    grid.sync();

    // ---- P2: rank + split-point for unit (b, rowgrp) ----
    {
        u64* keys = (u64*)(smem + 65536);    // overlays wabL/wacL (dead now)
        int* part = (int*)(smem + 98304);
        int b = blk >> 6, rowgrp = blk & 63;
        const float* t2b = t2 + (size_t)b * cN;
        for (int i = t; i < cN; i += 512)
            keys[i] = ((u64)f2sort(t2b[i]) << 32) | (u32)i;
        __syncthreads();
        int lane = t & 63, subset = t >> 6;  // 8 subsets x 512 keys
        int myrow = rowgrp * 64 + lane;
        u64 mykey = keys[myrow];
        u32 pk_hi = f2sort(-t1[(size_t)b * cN + myrow]);
        int s0 = subset * 512;
        int cnt = 0, cnt2 = 0;
#pragma unroll 8
        for (int kk = 0; kk < 512; ++kk) {
            u64 kv = keys[s0 + kk];
            cnt  += (kv < mykey) ? 1 : 0;
            cnt2 += ((u32)(kv >> 32) < pk_hi) ? 1 : 0;
        }
        part[subset * 64 + lane] = cnt;
        part[512 + subset * 64 + lane] = cnt2;
        __syncthreads();
        if (t < 64) {
            int jj = rowgrp * 64 + t;
            int rank = 0, pc = 0;
#pragma unroll
            for (int s = 0; s < 8; ++s) {
                rank += part[s * 64 + t];
                pc   += part[512 + s * 64 + t];
            }
            t2s[(size_t)b * cN + rank] = t2b[jj];
            idxs[(size_t)b * cN + rank] = jj;
            pidx[(size_t)b * cN + jj] = pc;
        }
    }

    // ---- P3: GEMM from persisted LDS A-tile; B fragments from L2 ----
    {
        int w = t >> 6, lane = t & 63, m = lane & 15, quad = lane >> 4;
        int rowblk = (w & 3) * 16;
        int g0 = (w >> 2) * 2;               // 2 col-groups per wave
        f32x4 acc0 = {0.f, 0.f, 0.f, 0.f}, acc1 = {0.f, 0.f, 0.f, 0.f};
        int arow_ = rowblk + m;
        const char* abase = smem + arow_ * 1024;
        unsigned swz = (unsigned)(arow_ & 7) << 4;
        const u16* bg0 = wab16 + (size_t)(g0 * 16 + m) * cD + quad * 8;
        const u16* bg1 = wab16 + (size_t)((g0 + 1) * 16 + m) * cD + quad * 8;
#pragma unroll 4
        for (int s = 0; s < 16; ++s) {
            bf16x8 av  = *(const bf16x8*)(abase + (((unsigned)(s * 64 + quad * 16)) ^ swz));
            bf16x8 bv0 = *(const bf16x8*)(bg0 + s * 32);
            bf16x8 bv1 = *(const bf16x8*)(bg1 + s * 32);
            acc0 = __builtin_amdgcn_mfma_f32_16x16x32_bf16(av, bv0, acc0, 0, 0, 0);
            acc1 = __builtin_amdgcn_mfma_f32_16x16x32_bf16(av, bv1, acc1, 0, 0, 0);
        }
        int rowbase = blk * 64;
#pragma unroll
        for (int r4 = 0; r4 < 4; ++r4) {
            int row = rowblk + quad * 4 + r4;
            h[(size_t)(rowbase + row) * cK + g0 * 16 + m]       = acc0[r4];
            h[(size_t)(rowbase + row) * cK + (g0 + 1) * 16 + m] = acc1[r4];
        }
    }
    __threadfence();
    grid.sync();

    // ---- P4: chunkscan — 4 chunks/block, waves 0-3 = E, waves 4-7 = G ----
    {
        int w = t >> 6, lane = t & 63;
        int unit = blk * 4 + (w & 3);        // 1024 (b,c) units
        int role = w >> 2;                   // 0 = E(suffix), 1 = G(prefix)
        int b = unit >> 8, c = unit & (cNC - 1);
        int base = b * cN + c * cCS;
        size_t rowbase = ((size_t)b * cNP + c * cCS) * cK;
        int sbase = b * cNP + c * cCS;
        float M2 = t2s[(size_t)b * cN + cN - 1];
        int   idxv = (lane < cCS) ? idxs[base + lane] : 0;
        float t2v  = (lane < cCS) ? t2s[base + lane] : 0.f;
        float hv[cCS];
#pragma unroll
        for (int i = 0; i < cCS; ++i) {
            int j = __shfl(idxv, i, 64);
            hv[i] = h[((size_t)b * cN + j) * cK + lane];
        }
        float slope = role ? 0.2f : 1.0f;
        float ev[cCS];
#pragma unroll
        for (int i = 0; i < cCS; ++i)
            ev[i] = __expf(slope * (__shfl(t2v, i, 64) - M2));
        if (role == 0) {
            if (c == cNC - 1) {
                EpL[((size_t)b * cNP + cN) * cK + lane] = 0.f;
                if (lane == 0) eps_l[b * cNP + cN] = 0.f;
            }
            float acc = 0.f, accs = 0.f;
#pragma unroll
            for (int i = cCS - 1; i >= 0; --i) {
                acc += ev[i] * hv[i]; accs += ev[i];
                EpL[rowbase + (size_t)i * cK + lane] = acc;
                if (lane == 0) eps_l[sbase + i] = accs;
            }
            chE[((size_t)b * cNC + c) * cK + lane] = acc;
            if (lane == 0) chEs[b * cNC + c] = accs;
        } else {
            if (c == cNC - 1) {
                GnL[((size_t)b * cNP + cN) * cK + lane] = 0.f;
                if (lane == 0) gns_l[b * cNP + cN] = 0.f;
            }
            float acc = 0.f, accs = 0.f;
#pragma unroll
            for (int i = 0; i < cCS; ++i) {
                GnL[rowbase + (size_t)i * cK + lane] = acc;
                if (lane == 0) gns_l[sbase + i] = accs;
                acc += ev[i] * hv[i]; accs += ev[i];
            }
            chG[((size_t)b * cNC + c) * cK + lane] = acc;
            if (lane == 0) chGs[b * cNC + c] = accs;
        }
    }
    __threadfence();
    grid.sync();

    // ---- P5: offsets (blocks 0-7; 8 waves x 32 chunks) ----
    if (blk < 8) {
        float (*wsum)[64] = (float(*)[64])(smem + 98304);
        int lane = t & 63, w = t >> 6;
        int dir = blk & 1;                   // 0 = E(suffix), 1 = G(prefix)
        int b = blk >> 1;
        const float* ch = dir ? chG : chE;
        float* of = dir ? ofG : ofE;
        int c0 = w * 32;
        float cv[32];
        float s = 0.f;
#pragma unroll
        for (int i = 0; i < 32; ++i) {
            cv[i] = ch[((size_t)b * cNC + c0 + i) * cK + lane];
            s += cv[i];
        }
        wsum[w][lane] = s;
        __syncthreads();
        float base = 0.f;
        if (dir == 0) { for (int w2 = w + 1; w2 < 8; ++w2) base += wsum[w2][lane]; }
        else          { for (int w2 = 0; w2 < w; ++w2) base += wsum[w2][lane]; }
        if (dir == 0) {
            float run = base;
#pragma unroll
            for (int i = 31; i >= 0; --i) {
                of[((size_t)b * cNC1 + c0 + i) * cK + lane] = run;
                run += cv[i];
            }
            if (w == 0) of[((size_t)b * cNC1 + cNC) * cK + lane] = 0.f;
        } else {
            float run = base;
#pragma unroll
            for (int i = 0; i < 32; ++i) {
                of[((size_t)b * cNC1 + c0 + i) * cK + lane] = run;
                run += cv[i];
            }
            if (w == 7) of[((size_t)b * cNC1 + cNC) * cK + lane] = run;
        }
        if (w == 0) {
            const float* chs = dir ? chGs : chEs;
            float* ofs = dir ? ofGs : ofEs;
            float e0 = chs[b * cNC + lane * 4 + 0];
            float e1 = chs[b * cNC + lane * 4 + 1];
            float e2 = chs[b * cNC + lane * 4 + 2];
            float e3 = chs[b * cNC + lane * 4 + 3];
            float p = e0 + e1 + e2 + e3;
            if (dir == 0) {
                float s2 = p;
#pragma unroll
                for (int off = 1; off < 64; off <<= 1) {
                    float tv = __shfl_down(s2, off, 64);
                    if (lane + off < 64) s2 += tv;
                }
                float excl = s2 - p;          // sum over lanes > lane
                ofs[b * cNC1 + lane * 4 + 0] = excl + e1 + e2 + e3;
                ofs[b * cNC1 + lane * 4 + 1] = excl + e2 + e3;
                ofs[b * cNC1 + lane * 4 + 2] = excl + e3;
                ofs[b * cNC1 + lane * 4 + 3] = excl;
                if (lane == 0) ofs[b * cNC1 + cNC] = 0.f;
            } else {
                float s2 = p;
#pragma unroll
                for (int off = 1; off < 64; off <<= 1) {
                    float tv = __shfl_up(s2, off, 64);
                    if (lane >= off) s2 += tv;
                }
                float excl = s2 - p;          // sum over lanes < lane
                ofs[b * cNC1 + lane * 4 + 0] = excl;
                ofs[b * cNC1 + lane * 4 + 1] = excl + e0;
                ofs[b * cNC1 + lane * 4 + 2] = excl + e0 + e1;
                ofs[b * cNC1 + lane * 4 + 3] = excl + e0 + e1 + e2;
                if (lane == 63) ofs[b * cNC1 + cNC] = s2;
            }
        }
    }
    __threadfence();
    grid.sync();

    // ---- P6: out — 64 rows/block, 8 rows/wave (unrolled for ILP) ----
    {
        int w = t >> 6, lane = t & 63;
        float bv = bias[lane];
#pragma unroll
        for (int i = 0; i < 8; ++i) {
            int r = blk * 64 + w * 8 + i;
            int b = r >> 12;
            float T1 = t1[r];
            float M2 = t2s[(size_t)b * cN + cN - 1];
            float smax = T1 + M2;
            float m = fmaxf(smax, 0.2f * smax);   // leaky_relu(smax) = row max
            float A  = __expf(smax - m);
            float Cc = __expf(0.2f * smax - m);
            int p = pidx[r];
            int c = p >> 4;
            size_t pr = ((size_t)b * cNP + p) * cK + lane;
            size_t cr = ((size_t)b * cNC1 + c) * cK + lane;
            float num = A * (EpL[pr] + ofE[cr]) + Cc * (GnL[pr] + ofG[cr]);
            float den = A * (eps_l[(size_t)b * cNP + p] + ofEs[b * cNC1 + c])
                      + Cc * (gns_l[(size_t)b * cNP + p] + ofGs[b * cNC1 + c]);
            out[(size_t)r * cK + lane] = num / den + bv;
        }
    }
}

// ===========================================================================
// FALLBACK path: round-3 5-kernel pipeline (used if cooperative launch is
// unavailable). Verified at 130.4 us.
// ===========================================================================
__global__ __launch_bounds__(256) void k_prep(
    const float* __restrict__ x, const float* __restrict__ Wa,
    const float* __restrict__ Wb, const float* __restrict__ wbb,
    const float* __restrict__ Wc, const float* __restrict__ wcb,
    u16* __restrict__ xb16, u16* __restrict__ wab16,
    float* __restrict__ t1, float* __restrict__ t2)
{
    __shared__ float wabL[cD], wacL[cD];
    int t = threadIdx.x;
    if (blockIdx.x >= 512) {
        int i4 = (((int)blockIdx.x - 512) * 256 + t) * 4;
        float4 v = *(const float4*)(Wa + i4);
        uint2 p = {pk2(v.x, v.y), pk2(v.z, v.w)};
        *(uint2*)(wab16 + i4) = p;
        return;
    }
    float s1a = 0.f, s2a = 0.f, s1b = 0.f, s2b = 0.f;
#pragma unroll 8
    for (int k = 0; k < cK; ++k) {
        float wbk = Wb[k], wck = Wc[k];
        float wa1 = Wa[k * cD + t];
        float wa2 = Wa[k * cD + t + 256];
        s1a += wa1 * wbk; s2a += wa1 * wck;
        s1b += wa2 * wbk; s2b += wa2 * wck;
    }
    wabL[t] = s1a; wacL[t] = s2a; wabL[t + 256] = s1b; wacL[t + 256] = s2b;
    __syncthreads();

    int w = t >> 6, lane = t & 63;
    int d1 = lane * 4, d2 = 256 + lane * 4;
    float4 wbA = *(const float4*)&wabL[d1], wbB = *(const float4*)&wabL[d2];
    float4 wcA = *(const float4*)&wacL[d1], wcB = *(const float4*)&wacL[d2];
    float wbbv = wbb[0], wcbv = wcb[0];
#pragma unroll 2
    for (int rr = 0; rr < 8; ++rr) {
        int row = blockIdx.x * 32 + w * 8 + rr;
        const float* xp = x + (size_t)row * cD;
        float4 a  = *(const float4*)(xp + d1);
        float4 bq = *(const float4*)(xp + d2);
        uint2 pa = {pk2(a.x, a.y), pk2(a.z, a.w)};
        uint2 pb = {pk2(bq.x, bq.y), pk2(bq.z, bq.w)};
        *(uint2*)(xb16 + (size_t)row * cD + d1) = pa;
        *(uint2*)(xb16 + (size_t)row * cD + d2) = pb;
        float p1 = a.x*wbA.x + a.y*wbA.y + a.z*wbA.z + a.w*wbA.w
                 + bq.x*wbB.x + bq.y*wbB.y + bq.z*wbB.z + bq.w*wbB.w;
        float p2 = a.x*wcA.x + a.y*wcA.y + a.z*wcA.z + a.w*wcA.w
                 + bq.x*wcB.x + bq.y*wcB.y + bq.z*wcB.z + bq.w*wcB.w;
#pragma unroll
        for (int off = 32; off > 0; off >>= 1) {
            p1 += __shfl_down(p1, off, 64);
            p2 += __shfl_down(p2, off, 64);
        }
        if (lane == 0) { t1[row] = p1 + wbbv; t2[row] = p2 + wcbv; }
    }
}

__global__ __launch_bounds__(256) void k_projrank(
    const u16* __restrict__ xb16, const u16* __restrict__ wab16,
    const float* __restrict__ t1, const float* __restrict__ t2,
    float* __restrict__ h, float* __restrict__ t2s, int* __restrict__ idxs,
    int* __restrict__ pidx)
{
    __shared__ __align__(16) u64 shbuf[4096 + 256];
    int t = threadIdx.x;
    if (blockIdx.x < 256) {
        u16* xs = (u16*)shbuf;
        u16* was = xs + 64 * 32;
        int rowbase = blockIdx.x * 64;
        int w = t >> 6, lane = t & 63, m = lane & 15, quad = lane >> 4;
        int grow = w * 16 + (lane >> 2);
        int gcol = (lane & 3) * 8;
        const u16* xg = xb16 + (size_t)(rowbase + grow) * cD + gcol;
        const u16* wg = wab16 + (size_t)grow * cD + gcol;
        int lidx = grow * 32 + gcol;

        f32x4 acc[4] = {{0.f,0.f,0.f,0.f},{0.f,0.f,0.f,0.f},
                        {0.f,0.f,0.f,0.f},{0.f,0.f,0.f,0.f}};
        uint4 xv = *(const uint4*)(xg);
        uint4 wv = *(const uint4*)(wg);
        for (int s = 0; s < 16; ++s) {
            __syncthreads();
            *(uint4*)&xs[lidx] = xv;
            *(uint4*)&was[lidx] = wv;
            if (s < 15) {
                xv = *(const uint4*)(xg + (s + 1) * 32);
                wv = *(const uint4*)(wg + (s + 1) * 32);
            }
            __syncthreads();
            bf16x8 av = *(const bf16x8*)&xs[(w * 16 + m) * 32 + quad * 8];
#pragma unroll
            for (int g = 0; g < 4; ++g) {
                bf16x8 bvv = *(const bf16x8*)&was[(g * 16 + m) * 32 + quad * 8];
                acc[g] = __builtin_amdgcn_mfma_f32_16x16x32_bf16(av, bvv, acc[g], 0, 0, 0);
            }
        }
#pragma unroll
        for (int g = 0; g < 4; ++g) {
#pragma unroll
            for (int r4 = 0; r4 < 4; ++r4) {
                int row = w * 16 + quad * 4 + r4;
                h[(size_t)(rowbase + row) * cK + g * 16 + m] = acc[g][r4];
            }
        }
    } else {
        u64* keys = shbuf;
        int* part = (int*)(shbuf + 4096);
        int rb = blockIdx.x - 256;
        int b = rb >> 6;
        int rowgrp = rb & 63;
        for (int i = t; i < cN; i += 256)
            keys[i] = ((u64)f2sort(t2[b * cN + i]) << 32) | (u32)i;
        __syncthreads();
        int lane = t & 63, subset = t >> 6;
        int myrow = rowgrp * 64 + lane;
        u64 mykey = keys[myrow];
        u32 pk_hi = f2sort(-t1[(size_t)b * cN + myrow]);
        int s0 = subset * 1024;
        int cnt = 0, cnt2 = 0;
#pragma unroll 8
        for (int kk = 0; kk < 1024; ++kk) {
            u64 kv = keys[s0 + kk];
            cnt  += (kv < mykey) ? 1 : 0;
            cnt2 += ((u32)(kv >> 32) < pk_hi) ? 1 : 0;
        }
        part[subset * 64 + lane] = cnt;
        part[256 + subset * 64 + lane] = cnt2;
        __syncthreads();
        if (t < 64) {
            int jj = rowgrp * 64 + t;
            int rank = part[t] + part[64 + t] + part[128 + t] + part[192 + t];
            int pc   = part[256 + t] + part[320 + t] + part[384 + t] + part[448 + t];
            t2s[b * cN + rank] = t2[b * cN + jj];
            idxs[b * cN + rank] = jj;
            pidx[b * cN + jj] = pc;
        }
    }
}

__global__ __launch_bounds__(64) void k_chunkscan(
    const float* __restrict__ t2s, const int* __restrict__ idxs,
    const float* __restrict__ h,
    float* __restrict__ EpL, float* __restrict__ GnL,
    float* __restrict__ eps_l, float* __restrict__ gns_l,
    float* __restrict__ chE, float* __restrict__ chG,
    float* __restrict__ chEs, float* __restrict__ chGs)
{
    int lane = threadIdx.x;
    int blk = blockIdx.x;
    int c = blk & (cNC - 1);
    int b = blk >> 8;
    int base = b * cN + c * cCS;
    size_t rowbase = ((size_t)b * cNP + c * cCS) * cK;
    int sbase = b * cNP + c * cCS;
    float M2 = t2s[b * cN + cN - 1];
    int   idxv = (lane < cCS) ? idxs[base + lane] : 0;
    float t2v  = (lane < cCS) ? t2s[base + lane] : 0.f;

    float hv[cCS];
#pragma unroll
    for (int i = 0; i < cCS; ++i) {
        int j = __shfl(idxv, i, 64);
        hv[i] = h[((size_t)b * cN + j) * cK + lane];
    }
    float ee[cCS], gg[cCS];
#pragma unroll
    for (int i = 0; i < cCS; ++i) {
        float d = __shfl(t2v, i, 64) - M2;
        ee[i] = __expf(d);
        gg[i] = __expf(0.2f * d);
    }
    if (c == cNC - 1) {
        EpL[((size_t)b * cNP + cN) * cK + lane] = 0.f;
        GnL[((size_t)b * cNP + cN) * cK + lane] = 0.f;
        if (lane == 0) { eps_l[b * cNP + cN] = 0.f; gns_l[b * cNP + cN] = 0.f; }
    }
    float acc = 0.f, accs = 0.f;
#pragma unroll
    for (int i = cCS - 1; i >= 0; --i) {
        acc += ee[i] * hv[i]; accs += ee[i];
        EpL[rowbase + (size_t)i * cK + lane] = acc;
        if (lane == 0) eps_l[sbase + i] = accs;
    }
    chE[((size_t)b * cNC + c) * cK + lane] = acc;
    if (lane == 0) chEs[b * cNC + c] = accs;
    acc = 0.f; accs = 0.f;
#pragma unroll
    for (int i = 0; i < cCS; ++i) {
        GnL[rowbase + (size_t)i * cK + lane] = acc;
        if (lane == 0) gns_l[sbase + i] = accs;
        acc += gg[i] * hv[i]; accs += gg[i];
    }
    chG[((size_t)b * cNC + c) * cK + lane] = acc;
    if (lane == 0) chGs[b * cNC + c] = accs;
}

__global__ __launch_bounds__(1024) void k_offsets(
    const float* __restrict__ chE, const float* __restrict__ chG,
    const float* __restrict__ chEs, const float* __restrict__ chGs,
    float* __restrict__ ofE, float* __restrict__ ofG,
    float* __restrict__ ofEs, float* __restrict__ ofGs)
{
    __shared__ float wsum[16][64];
    int t = threadIdx.x;
    int lane = t & 63, w = t >> 6;
    int dir = blockIdx.x & 1;
    int b = blockIdx.x >> 1;
    const float* ch = dir ? chG : chE;
    float* of = dir ? ofG : ofE;
    int c0 = w * 16;

    float cv[16];
    float s = 0.f;
#pragma unroll
    for (int i = 0; i < 16; ++i) {
        cv[i] = ch[((size_t)b * cNC + c0 + i) * cK + lane];
        s += cv[i];
    }
    wsum[w][lane] = s;
    __syncthreads();
    float base = 0.f;
    if (dir == 0) { for (int w2 = w + 1; w2 < 16; ++w2) base += wsum[w2][lane]; }
    else          { for (int w2 = 0; w2 < w; ++w2) base += wsum[w2][lane]; }

    if (dir == 0) {
        float run = base;
#pragma unroll
        for (int i = 15; i >= 0; --i) {
            of[((size_t)b * cNC1 + c0 + i) * cK + lane] = run;
            run += cv[i];
        }
        if (w == 0) of[((size_t)b * cNC1 + cNC) * cK + lane] = 0.f;
    } else {
        float run = base;
#pragma unroll
        for (int i = 0; i < 16; ++i) {
            of[((size_t)b * cNC1 + c0 + i) * cK + lane] = run;
            run += cv[i];
        }
        if (w == 15) of[((size_t)b * cNC1 + cNC) * cK + lane] = run;
    }

    if (w == 0) {
        const float* chs = dir ? chGs : chEs;
        float* ofs = dir ? ofGs : ofEs;
        float e0 = chs[b * cNC + lane * 4 + 0];
        float e1 = chs[b * cNC + lane * 4 + 1];
        float e2 = chs[b * cNC + lane * 4 + 2];
        float e3 = chs[b * cNC + lane * 4 + 3];
        float p = e0 + e1 + e2 + e3;
        if (dir == 0) {
            float s2 = p;
#pragma unroll
            for (int off = 1; off < 64; off <<= 1) {
                float tv = __shfl_down(s2, off, 64);
                if (lane + off < 64) s2 += tv;
            }
            float excl = s2 - p;
            ofs[b * cNC1 + lane * 4 + 0] = excl + e1 + e2 + e3;
            ofs[b * cNC1 + lane * 4 + 1] = excl + e2 + e3;
            ofs[b * cNC1 + lane * 4 + 2] = excl + e3;
            ofs[b * cNC1 + lane * 4 + 3] = excl;
            if (lane == 0) ofs[b * cNC1 + cNC] = 0.f;
        } else {
            float s2 = p;
#pragma unroll
            for (int off = 1; off < 64; off <<= 1) {
                float tv = __shfl_up(s2, off, 64);
                if (lane >= off) s2 += tv;
            }
            float excl = s2 - p;
            ofs[b * cNC1 + lane * 4 + 0] = excl;
            ofs[b * cNC1 + lane * 4 + 1] = excl + e0;
            ofs[b * cNC1 + lane * 4 + 2] = excl + e0 + e1;
            ofs[b * cNC1 + lane * 4 + 3] = excl + e0 + e1 + e2;
            if (lane == 63) ofs[b * cNC1 + cNC] = s2;
        }
    }
}

__global__ __launch_bounds__(256) void k_out(
    const float* __restrict__ t1, const float* __restrict__ t2s,
    const int* __restrict__ pidx,
    const float* __restrict__ EpL, const float* __restrict__ GnL,
    const float* __restrict__ eps_l, const float* __restrict__ gns_l,
    const float* __restrict__ ofE, const float* __restrict__ ofG,
    const float* __restrict__ ofEs, const float* __restrict__ ofGs,
    const float* __restrict__ bias, float* __restrict__ out)
{
    int tid = threadIdx.x;
    int lane = tid & 63;
    int r = blockIdx.x * 4 + (tid >> 6);
    int b = r >> 12;
    float T1 = t1[r];
    float M2 = t2s[b * cN + cN - 1];
    float smax = T1 + M2;
    float m = fmaxf(smax, 0.2f * smax);
    float A  = __expf(smax - m);
    float Cc = __expf(0.2f * smax - m);
    int p = pidx[r];
    int c = p >> 4;
    size_t pr = ((size_t)b * cNP + p) * cK + lane;
    size_t cr = ((size_t)b * cNC1 + c) * cK + lane;
    float num = A * (EpL[pr] + ofE[cr]) + Cc * (GnL[pr] + ofG[cr]);
    float den = A * (eps_l[(size_t)b * cNP + p] + ofEs[b * cNC1 + c])
              + Cc * (gns_l[(size_t)b * cNP + p] + ofGs[b * cNC1 + c]);
    out[(size_t)r * cK + lane] = num / den + bias[lane];
}

// ---------------------------------------------------------------------------
extern "C" void kernel_launch(void* const* d_in, const int* in_sizes, int n_in,
                              void* d_out, int out_size, void* d_ws, size_t ws_size,
                              hipStream_t stream)
{
    const float* x    = (const float*)d_in[0];
    const float* Wa   = (const float*)d_in[1];
    const float* Wb   = (const float*)d_in[2];
    const float* wbb  = (const float*)d_in[3];
    const float* Wc   = (const float*)d_in[4];
    const float* wcb  = (const float*)d_in[5];
    const float* bias = (const float*)d_in[6];
    float* out = (float*)d_out;

    float* ws = (float*)d_ws;
    float* h     = ws + OFF_H;
    float* t1    = ws + OFF_T1;
    float* t2    = ws + OFF_T2;
    float* t2s   = ws + OFF_T2S;
    int*   idxs  = (int*)(ws + OFF_IDX);
    int*   pidx  = (int*)(ws + OFF_P);
    float* EpL   = ws + OFF_EPL;
    float* GnL   = ws + OFF_GNL;
    float* eps_l = ws + OFF_EPS;
    float* gns_l = ws + OFF_GNS;
    float* chE   = ws + OFF_CHE;
    float* chG   = ws + OFF_CHG;
    float* chEs  = ws + OFF_CHES;
    float* chGs  = ws + OFF_CHGS;
    float* ofE   = ws + OFF_OFE;
    float* ofG   = ws + OFF_OFG;
    float* ofEs  = ws + OFF_OFES;
    float* ofGs  = ws + OFF_OFGS;
    u16*   xb16  = (u16*)(ws + OFF_XB16);
    u16*   wab16 = (u16*)(ws + OFF_WB16);

    constexpr unsigned SMEM = 102400;   // 64K A-tile + 32K keys + 4K part + 2K spare
    static int use_coop = -1;
    if (use_coop < 0) {
        hipError_t e = hipFuncSetAttribute((const void*)k_mega,
            hipFuncAttributeMaxDynamicSharedMemorySize, (int)SMEM);
        use_coop = (e == hipSuccess) ? 1 : 0;
    }
    if (use_coop) {
        void* args[] = {
            (void*)&x, (void*)&Wa, (void*)&Wb, (void*)&wbb, (void*)&Wc, (void*)&wcb,
            (void*)&bias, (void*)&out, (void*)&t1, (void*)&t2, (void*)&t2s,
            (void*)&idxs, (void*)&pidx, (void*)&wab16, (void*)&h,
            (void*)&EpL, (void*)&GnL, (void*)&eps_l, (void*)&gns_l,
            (void*)&chE, (void*)&chG, (void*)&chEs, (void*)&chGs,
            (void*)&ofE, (void*)&ofG, (void*)&ofEs, (void*)&ofGs };
        hipError_t e = hipLaunchCooperativeKernel((const void*)k_mega,
            dim3(256), dim3(512), args, SMEM, stream);
        if (e == hipSuccess) return;
        use_coop = 0;   // fall through to classic path
    }

    k_prep<<<544, 256, 0, stream>>>(x, Wa, Wb, wbb, Wc, wcb, xb16, wab16, t1, t2);
    k_projrank<<<512, 256, 0, stream>>>(xb16, wab16, t1, t2, h, t2s, idxs, pidx);
    k_chunkscan<<<cB * cNC, 64, 0, stream>>>(t2s, idxs, h, EpL, GnL, eps_l, gns_l,
                                             chE, chG, chEs, chGs);
    k_offsets<<<cB * 2, 1024, 0, stream>>>(chE, chG, chEs, chGs, ofE, ofG, ofEs, ofGs);
    k_out<<<cNB / 4, 256, 0, stream>>>(t1, t2s, pidx, EpL, GnL, eps_l, gns_l,
                                       ofE, ofG, ofEs, ofGs, bias, out);
}

// Round 5
// 126.674 us; speedup vs baseline: 3.2677x; 3.2677x over previous
//
#include <hip/hip_runtime.h>
#include <hip/hip_bf16.h>

// Problem constants
constexpr int cB = 4;
constexpr int cN = 4096;
constexpr int cD = 512;
constexpr int cK = 64;
constexpr int cNB = cB * cN;       // 16384 rows
constexpr int cNP = cN + 1;        // 4097 prefix rows
constexpr int cCS = 16;            // chunk size for scans
constexpr int cNC = cN / cCS;      // 256 chunks per batch
constexpr int cNC1 = cNC + 1;      // 257

typedef unsigned short u16;
typedef unsigned int u32;
typedef unsigned long long u64;
typedef __bf16 bf16x8 __attribute__((ext_vector_type(8)));
typedef float f32x4 __attribute__((ext_vector_type(4)));

// ---- workspace layout (in floats) ----
constexpr size_t OFF_H    = 0;                                  // cNB*cK
constexpr size_t OFF_T1   = OFF_H    + (size_t)cNB * cK;        // cNB
constexpr size_t OFF_T2   = OFF_T1   + cNB;                     // cNB
constexpr size_t OFF_T2S  = OFF_T2   + cNB;                     // cNB (sorted)
constexpr size_t OFF_IDX  = OFF_T2S  + cNB;                     // cNB (int)
constexpr size_t OFF_P    = OFF_IDX  + cNB;                     // cNB (int) split point per row
constexpr size_t OFF_EPL  = OFF_P    + cNB;                     // cB*cNP*cK
constexpr size_t OFF_GNL  = OFF_EPL  + (size_t)cB * cNP * cK;   // cB*cNP*cK
constexpr size_t OFF_EPS  = OFF_GNL  + (size_t)cB * cNP * cK;   // cB*cNP
constexpr size_t OFF_GNS  = OFF_EPS  + (size_t)cB * cNP;        // cB*cNP
constexpr size_t OFF_CHE  = OFF_GNS  + (size_t)cB * cNP;        // cB*cNC*cK
constexpr size_t OFF_CHG  = OFF_CHE  + (size_t)cB * cNC * cK;
constexpr size_t OFF_CHES = OFF_CHG  + (size_t)cB * cNC * cK;   // cB*cNC
constexpr size_t OFF_CHGS = OFF_CHES + (size_t)cB * cNC;
constexpr size_t OFF_OFE  = OFF_CHGS + (size_t)cB * cNC;        // cB*cNC1*cK (fallback only)
constexpr size_t OFF_OFG  = OFF_OFE  + (size_t)cB * cNC1 * cK;
constexpr size_t OFF_OFES = OFF_OFG  + (size_t)cB * cNC1 * cK;  // cB*cNC1
constexpr size_t OFF_OFGS = OFF_OFES + (size_t)cB * cNC1;
constexpr size_t OFF_WB16 = OFF_OFGS + (size_t)cB * cNC1;       // cK*cD u16

__device__ __forceinline__ u16 f2bf(float f) {
    unsigned u = __float_as_uint(f);
    u += 0x7fffu + ((u >> 16) & 1u);   // RNE
    return (u16)(u >> 16);
}
__device__ __forceinline__ u32 pk2(float a, float b) {
    return (u32)f2bf(a) | ((u32)f2bf(b) << 16);
}
// monotone float -> sortable uint (ascending)
__device__ __forceinline__ u32 f2sort(float f) {
    u32 b = __float_as_uint(f);
    u32 mask = (u32)((int)b >> 31);
    return b ^ (mask | 0x80000000u);
}

// ---------------------------------------------------------------------------
// k_prep (544 blocks): blocks <512: one pass over x -> exact f32 t1/t2 via
// in-block fold of Wa with Wb/Wc (no xb16 write -- GEMM reads x directly).
// Blocks >=512: Wa -> wab16 (bf16 B operand).
// ---------------------------------------------------------------------------
__global__ __launch_bounds__(256) void k_prep(
    const float* __restrict__ x, const float* __restrict__ Wa,
    const float* __restrict__ Wb, const float* __restrict__ wbb,
    const float* __restrict__ Wc, const float* __restrict__ wcb,
    u16* __restrict__ wab16, float* __restrict__ t1, float* __restrict__ t2)
{
    __shared__ float wabL[cD], wacL[cD];
    int t = threadIdx.x;
    if (blockIdx.x >= 512) {           // wprep slice: 32 blocks x 256 x 4 elems
        int i4 = (((int)blockIdx.x - 512) * 256 + t) * 4;
        float4 v = *(const float4*)(Wa + i4);
        uint2 p = {pk2(v.x, v.y), pk2(v.z, v.w)};
        *(uint2*)(wab16 + i4) = p;
        return;
    }
    float s1a = 0.f, s2a = 0.f, s1b = 0.f, s2b = 0.f;
#pragma unroll 8
    for (int k = 0; k < cK; ++k) {
        float wbk = Wb[k], wck = Wc[k];
        float wa1 = Wa[k * cD + t];
        float wa2 = Wa[k * cD + t + 256];
        s1a += wa1 * wbk; s2a += wa1 * wck;
        s1b += wa2 * wbk; s2b += wa2 * wck;
    }
    wabL[t] = s1a; wacL[t] = s2a; wabL[t + 256] = s1b; wacL[t + 256] = s2b;
    __syncthreads();

    int w = t >> 6, lane = t & 63;
    int d1 = lane * 4, d2 = 256 + lane * 4;
    float4 wbA = *(const float4*)&wabL[d1], wbB = *(const float4*)&wabL[d2];
    float4 wcA = *(const float4*)&wacL[d1], wcB = *(const float4*)&wacL[d2];
    float wbbv = wbb[0], wcbv = wcb[0];
#pragma unroll 2
    for (int rr = 0; rr < 8; ++rr) {
        int row = blockIdx.x * 32 + w * 8 + rr;
        const float* xp = x + (size_t)row * cD;
        float4 a  = *(const float4*)(xp + d1);
        float4 bq = *(const float4*)(xp + d2);
        float p1 = a.x*wbA.x + a.y*wbA.y + a.z*wbA.z + a.w*wbA.w
                 + bq.x*wbB.x + bq.y*wbB.y + bq.z*wbB.z + bq.w*wbB.w;
        float p2 = a.x*wcA.x + a.y*wcA.y + a.z*wcA.z + a.w*wcA.w
                 + bq.x*wcB.x + bq.y*wcB.y + bq.z*wcB.z + bq.w*wcB.w;
#pragma unroll
        for (int off = 32; off > 0; off >>= 1) {
            p1 += __shfl_down(p1, off, 64);
            p2 += __shfl_down(p2, off, 64);
        }
        if (lane == 0) { t1[row] = p1 + wbbv; t2[row] = p2 + wcbv; }
    }
}

// ---------------------------------------------------------------------------
// k_projrank (512 blocks): blocks <256 do the bf16-MFMA GEMM tile (64 rows),
// staging A from x (f32 -> RNE bf16 in-register, bit-identical to pk2 path);
// blocks >=256 do brute-force rank (LDS-staged composite keys) with the
// fused split-point count (pidx).
// ---------------------------------------------------------------------------
__global__ __launch_bounds__(256) void k_projrank(
    const float* __restrict__ x, const u16* __restrict__ wab16,
    const float* __restrict__ t1, const float* __restrict__ t2,
    float* __restrict__ h, float* __restrict__ t2s, int* __restrict__ idxs,
    int* __restrict__ pidx)
{
    __shared__ __align__(16) u64 shbuf[4096 + 256];   // 34 KB: keys + part (512 ints)
    int t = threadIdx.x;
    if (blockIdx.x < 256) {
        u16* xs = (u16*)shbuf;
        u16* was = xs + 64 * 32;
        int rowbase = blockIdx.x * 64;
        int w = t >> 6, lane = t & 63, m = lane & 15, quad = lane >> 4;
        int grow = w * 16 + (lane >> 2);
        int gcol = (lane & 3) * 8;
        const float* xg = x + (size_t)(rowbase + grow) * cD + gcol;
        const u16* wg = wab16 + (size_t)grow * cD + gcol;
        int lidx = grow * 32 + gcol;

        f32x4 acc[4] = {{0.f,0.f,0.f,0.f},{0.f,0.f,0.f,0.f},
                        {0.f,0.f,0.f,0.f},{0.f,0.f,0.f,0.f}};
        float4 xa = *(const float4*)(xg);
        float4 xb2 = *(const float4*)(xg + 4);
        uint4 wv = *(const uint4*)(wg);
        for (int s = 0; s < 16; ++s) {
            __syncthreads();
            uint4 xv = {pk2(xa.x, xa.y), pk2(xa.z, xa.w),
                        pk2(xb2.x, xb2.y), pk2(xb2.z, xb2.w)};
            *(uint4*)&xs[lidx] = xv;
            *(uint4*)&was[lidx] = wv;
            if (s < 15) {
                xa  = *(const float4*)(xg + (s + 1) * 32);
                xb2 = *(const float4*)(xg + (s + 1) * 32 + 4);
                wv = *(const uint4*)(wg + (s + 1) * 32);
            }
            __syncthreads();
            bf16x8 av = *(const bf16x8*)&xs[(w * 16 + m) * 32 + quad * 8];
#pragma unroll
            for (int g = 0; g < 4; ++g) {
                bf16x8 bvv = *(const bf16x8*)&was[(g * 16 + m) * 32 + quad * 8];
                acc[g] = __builtin_amdgcn_mfma_f32_16x16x32_bf16(av, bvv, acc[g], 0, 0, 0);
            }
        }
#pragma unroll
        for (int g = 0; g < 4; ++g) {
#pragma unroll
            for (int r4 = 0; r4 < 4; ++r4) {
                int row = w * 16 + quad * 4 + r4;
                h[(size_t)(rowbase + row) * cK + g * 16 + m] = acc[g][r4];
            }
        }
    } else {
        u64* keys = shbuf;
        int* part = (int*)(shbuf + 4096);   // 512 ints
        int rb = blockIdx.x - 256;
        int b = rb >> 6;
        int rowgrp = rb & 63;
        for (int i = t; i < cN; i += 256)
            keys[i] = ((u64)f2sort(t2[b * cN + i]) << 32) | (u32)i;
        __syncthreads();
        int lane = t & 63, subset = t >> 6;
        int myrow = rowgrp * 64 + lane;
        u64 mykey = keys[myrow];
        u32 pk_hi = f2sort(-t1[(size_t)b * cN + myrow]);  // p-threshold hi word
        int s0 = subset * 1024;
        int cnt = 0, cnt2 = 0;
#pragma unroll 8
        for (int kk = 0; kk < 1024; ++kk) {
            u64 kv = keys[s0 + kk];
            cnt  += (kv < mykey) ? 1 : 0;
            cnt2 += ((u32)(kv >> 32) < pk_hi) ? 1 : 0;
        }
        part[subset * 64 + lane] = cnt;
        part[256 + subset * 64 + lane] = cnt2;
        __syncthreads();
        if (t < 64) {
            int jj = rowgrp * 64 + t;
            int rank = part[t] + part[64 + t] + part[128 + t] + part[192 + t];
            int pc   = part[256 + t] + part[320 + t] + part[384 + t] + part[448 + t];
            t2s[b * cN + rank] = t2[b * cN + jj];
            idxs[b * cN + rank] = jj;
            pidx[b * cN + jj] = pc;
        }
    }
}

// ---------------------------------------------------------------------------
// k_chunkscan: 2048 single-wave blocks; even blocks do the E (suffix) scan,
// odd blocks the G (prefix) scan of the same (batch, chunk) unit -> 8
// waves/CU for latency hiding, adjacent blocks share L2-hot h gathers.
// ---------------------------------------------------------------------------
__global__ __launch_bounds__(64) void k_chunkscan(
    const float* __restrict__ t2s, const int* __restrict__ idxs,
    const float* __restrict__ h,
    float* __restrict__ EpL, float* __restrict__ GnL,
    float* __restrict__ eps_l, float* __restrict__ gns_l,
    float* __restrict__ chE, float* __restrict__ chG,
    float* __restrict__ chEs, float* __restrict__ chGs)
{
    int lane = threadIdx.x;
    int role = blockIdx.x & 1;         // 0 = E(suffix), 1 = G(prefix)
    int unit = blockIdx.x >> 1;
    int c = unit & (cNC - 1);
    int b = unit >> 8;
    int base = b * cN + c * cCS;
    size_t rowbase = ((size_t)b * cNP + c * cCS) * cK;
    int sbase = b * cNP + c * cCS;
    float M2 = t2s[b * cN + cN - 1];
    int   idxv = (lane < cCS) ? idxs[base + lane] : 0;
    float t2v  = (lane < cCS) ? t2s[base + lane] : 0.f;

    float hv[cCS];
#pragma unroll
    for (int i = 0; i < cCS; ++i) {
        int j = __shfl(idxv, i, 64);
        hv[i] = h[((size_t)b * cN + j) * cK + lane];
    }
    float slope = role ? 0.2f : 1.0f;
    float ev[cCS];
#pragma unroll
    for (int i = 0; i < cCS; ++i)
        ev[i] = __expf(slope * (__shfl(t2v, i, 64) - M2));

    if (role == 0) {
        if (c == cNC - 1) {
            EpL[((size_t)b * cNP + cN) * cK + lane] = 0.f;
            if (lane == 0) eps_l[b * cNP + cN] = 0.f;
        }
        float acc = 0.f, accs = 0.f;
#pragma unroll
        for (int i = cCS - 1; i >= 0; --i) {
            acc += ev[i] * hv[i]; accs += ev[i];
            EpL[rowbase + (size_t)i * cK + lane] = acc;
            if (lane == 0) eps_l[sbase + i] = accs;
        }
        chE[((size_t)b * cNC + c) * cK + lane] = acc;
        if (lane == 0) chEs[b * cNC + c] = accs;
    } else {
        if (c == cNC - 1) {
            GnL[((size_t)b * cNP + cN) * cK + lane] = 0.f;
            if (lane == 0) gns_l[b * cNP + cN] = 0.f;
        }
        float acc = 0.f, accs = 0.f;
#pragma unroll
        for (int i = 0; i < cCS; ++i) {
            GnL[rowbase + (size_t)i * cK + lane] = acc;
            if (lane == 0) gns_l[sbase + i] = accs;
            acc += ev[i] * hv[i]; accs += ev[i];
        }
        chG[((size_t)b * cNC + c) * cK + lane] = acc;
        if (lane == 0) chGs[b * cNC + c] = accs;
    }
}

// ---------------------------------------------------------------------------
// k_outf: 256 blocks x 256 thr x 64 rows. Per-block prelude rebuilds the
// batch's offset tables (ofE/ofG suffix/prefix over 256 chunks + scalars)
// in 135 KB dynamic LDS from chE/chG -- replaces the k_offsets kernel and
// its launch boundary. Main loop: 16 rows/wave, gather + combine.
// ---------------------------------------------------------------------------
constexpr unsigned SMEM_OUT = 134664;
__global__ __launch_bounds__(256, 1) void k_outf(
    const float* __restrict__ t1, const float* __restrict__ t2s,
    const int* __restrict__ pidx,
    const float* __restrict__ EpL, const float* __restrict__ GnL,
    const float* __restrict__ eps_l, const float* __restrict__ gns_l,
    const float* __restrict__ chE, const float* __restrict__ chG,
    const float* __restrict__ chEs, const float* __restrict__ chGs,
    const float* __restrict__ bias, float* __restrict__ out)
{
    extern __shared__ char sm[];
    float (*ofEl)[64] = (float(*)[64])(sm);                 // 257*64
    float (*ofGl)[64] = (float(*)[64])(sm + 65792);         // 257*64
    float* ofEsL      = (float*)(sm + 131584);              // 257
    float* ofGsL      = (float*)(sm + 132612);              // 257
    float (*wsum)[64] = (float(*)[64])(sm + 133640);        // 4*64

    int t = threadIdx.x, lane = t & 63, w = t >> 6;
    int blk = blockIdx.x;
    int b = blk >> 6;
    const float* chEb = chE + (size_t)b * cNC * cK;
    const float* chGb = chG + (size_t)b * cNC * cK;
    int c0 = w * 64;

    // ---- E suffix scan (vector) + scalar scans on waves 0/1 ----
    {
        float cv[64]; float s = 0.f;
#pragma unroll
        for (int i = 0; i < 64; ++i) { cv[i] = chEb[(size_t)(c0 + i) * cK + lane]; s += cv[i]; }
        wsum[w][lane] = s;
        if (w == 0) {
            float e0 = chEs[b*cNC + lane*4+0], e1 = chEs[b*cNC + lane*4+1];
            float e2 = chEs[b*cNC + lane*4+2], e3 = chEs[b*cNC + lane*4+3];
            float p = e0+e1+e2+e3, s2 = p;
#pragma unroll
            for (int off = 1; off < 64; off <<= 1) {
                float tv = __shfl_down(s2, off, 64);
                if (lane + off < 64) s2 += tv;
            }
            float excl = s2 - p;                  // sum over lanes > lane
            ofEsL[lane*4+0] = excl + e1 + e2 + e3;
            ofEsL[lane*4+1] = excl + e2 + e3;
            ofEsL[lane*4+2] = excl + e3;
            ofEsL[lane*4+3] = excl;
            if (lane == 0) ofEsL[cNC] = 0.f;
        } else if (w == 1) {
            float e0 = chGs[b*cNC + lane*4+0], e1 = chGs[b*cNC + lane*4+1];
            float e2 = chGs[b*cNC + lane*4+2], e3 = chGs[b*cNC + lane*4+3];
            float p = e0+e1+e2+e3, s2 = p;
#pragma unroll
            for (int off = 1; off < 64; off <<= 1) {
                float tv = __shfl_up(s2, off, 64);
                if (lane >= off) s2 += tv;
            }
            float excl = s2 - p;                  // sum over lanes < lane
            ofGsL[lane*4+0] = excl;
            ofGsL[lane*4+1] = excl + e0;
            ofGsL[lane*4+2] = excl + e0 + e1;
            ofGsL[lane*4+3] = excl + e0 + e1 + e2;
            if (lane == 63) ofGsL[cNC] = s2;
        }
        __syncthreads();
        float base = 0.f;
        for (int w2 = w + 1; w2 < 4; ++w2) base += wsum[w2][lane];
        float run = base;
#pragma unroll
        for (int i = 63; i >= 0; --i) { ofEl[c0 + i][lane] = run; run += cv[i]; }
        if (w == 0) ofEl[cNC][lane] = 0.f;
    }
    __syncthreads();    // wsum reuse guard (base reads done)
    // ---- G prefix scan (vector) ----
    {
        float cv[64]; float s = 0.f;
#pragma unroll
        for (int i = 0; i < 64; ++i) { cv[i] = chGb[(size_t)(c0 + i) * cK + lane]; s += cv[i]; }
        wsum[w][lane] = s;
        __syncthreads();
        float base = 0.f;
        for (int w2 = 0; w2 < w; ++w2) base += wsum[w2][lane];
        float run = base;
#pragma unroll
        for (int i = 0; i < 64; ++i) { ofGl[c0 + i][lane] = run; run += cv[i]; }
        if (w == 3) ofGl[cNC][lane] = run;
    }
    __syncthreads();

    // ---- main: 64 rows/block, 16 rows/wave ----
    float bv = bias[lane];
    float M2 = t2s[(size_t)b * cN + cN - 1];
    int r0 = blk * 64 + w * 16;
    const float* epsb = eps_l + (size_t)b * cNP;
    const float* gnsb = gns_l + (size_t)b * cNP;
#pragma unroll 8
    for (int i = 0; i < 16; ++i) {
        int r = r0 + i;
        float T1 = t1[r];
        float smax = T1 + M2;
        float m = fmaxf(smax, 0.2f * smax);      // leaky_relu(smax) = row max
        float A  = __expf(smax - m);
        float Cc = __expf(0.2f * smax - m);
        int p = pidx[r];
        int c = p >> 4;
        size_t pr = ((size_t)b * cNP + p) * cK + lane;
        float num = A * (EpL[pr] + ofEl[c][lane]) + Cc * (GnL[pr] + ofGl[c][lane]);
        float den = A * (epsb[p] + ofEsL[c]) + Cc * (gnsb[p] + ofGsL[c]);
        out[(size_t)r * cK + lane] = num / den + bv;
    }
}

// ---------------------------------------------------------------------------
// Fallback pair (used only if the 135 KB LDS attribute is unavailable):
// round-3 k_offsets + k_out.
// ---------------------------------------------------------------------------
__global__ __launch_bounds__(1024) void k_offsets(
    const float* __restrict__ chE, const float* __restrict__ chG,
    const float* __restrict__ chEs, const float* __restrict__ chGs,
    float* __restrict__ ofE, float* __restrict__ ofG,
    float* __restrict__ ofEs, float* __restrict__ ofGs)
{
    __shared__ float wsum[16][64];
    int t = threadIdx.x;
    int lane = t & 63, w = t >> 6;
    int dir = blockIdx.x & 1;
    int b = blockIdx.x >> 1;
    const float* ch = dir ? chG : chE;
    float* of = dir ? ofG : ofE;
    int c0 = w * 16;

    float cv[16];
    float s = 0.f;
#pragma unroll
    for (int i = 0; i < 16; ++i) {
        cv[i] = ch[((size_t)b * cNC + c0 + i) * cK + lane];
        s += cv[i];
    }
    wsum[w][lane] = s;
    __syncthreads();
    float base = 0.f;
    if (dir == 0) { for (int w2 = w + 1; w2 < 16; ++w2) base += wsum[w2][lane]; }
    else          { for (int w2 = 0; w2 < w; ++w2) base += wsum[w2][lane]; }

    if (dir == 0) {
        float run = base;
#pragma unroll
        for (int i = 15; i >= 0; --i) {
            of[((size_t)b * cNC1 + c0 + i) * cK + lane] = run;
            run += cv[i];
        }
        if (w == 0) of[((size_t)b * cNC1 + cNC) * cK + lane] = 0.f;
    } else {
        float run = base;
#pragma unroll
        for (int i = 0; i < 16; ++i) {
            of[((size_t)b * cNC1 + c0 + i) * cK + lane] = run;
            run += cv[i];
        }
        if (w == 15) of[((size_t)b * cNC1 + cNC) * cK + lane] = run;
    }

    if (w == 0) {
        const float* chs = dir ? chGs : chEs;
        float* ofs = dir ? ofGs : ofEs;
        float e0 = chs[b * cNC + lane * 4 + 0];
        float e1 = chs[b * cNC + lane * 4 + 1];
        float e2 = chs[b * cNC + lane * 4 + 2];
        float e3 = chs[b * cNC + lane * 4 + 3];
        float p = e0 + e1 + e2 + e3;
        if (dir == 0) {
            float s2 = p;
#pragma unroll
            for (int off = 1; off < 64; off <<= 1) {
                float tv = __shfl_down(s2, off, 64);
                if (lane + off < 64) s2 += tv;
            }
            float excl = s2 - p;
            ofs[b * cNC1 + lane * 4 + 0] = excl + e1 + e2 + e3;
            ofs[b * cNC1 + lane * 4 + 1] = excl + e2 + e3;
            ofs[b * cNC1 + lane * 4 + 2] = excl + e3;
            ofs[b * cNC1 + lane * 4 + 3] = excl;
            if (lane == 0) ofs[b * cNC1 + cNC] = 0.f;
        } else {
            float s2 = p;
#pragma unroll
            for (int off = 1; off < 64; off <<= 1) {
                float tv = __shfl_up(s2, off, 64);
                if (lane >= off) s2 += tv;
            }
            float excl = s2 - p;
            ofs[b * cNC1 + lane * 4 + 0] = excl;
            ofs[b * cNC1 + lane * 4 + 1] = excl + e0;
            ofs[b * cNC1 + lane * 4 + 2] = excl + e0 + e1;
            ofs[b * cNC1 + lane * 4 + 3] = excl + e0 + e1 + e2;
            if (lane == 63) ofs[b * cNC1 + cNC] = s2;
        }
    }
}

__global__ __launch_bounds__(256) void k_out(
    const float* __restrict__ t1, const float* __restrict__ t2s,
    const int* __restrict__ pidx,
    const float* __restrict__ EpL, const float* __restrict__ GnL,
    const float* __restrict__ eps_l, const float* __restrict__ gns_l,
    const float* __restrict__ ofE, const float* __restrict__ ofG,
    const float* __restrict__ ofEs, const float* __restrict__ ofGs,
    const float* __restrict__ bias, float* __restrict__ out)
{
    int tid = threadIdx.x;
    int lane = tid & 63;
    int r = blockIdx.x * 4 + (tid >> 6);
    int b = r >> 12;
    float T1 = t1[r];
    float M2 = t2s[b * cN + cN - 1];
    float smax = T1 + M2;
    float m = fmaxf(smax, 0.2f * smax);
    float A  = __expf(smax - m);
    float Cc = __expf(0.2f * smax - m);
    int p = pidx[r];
    int c = p >> 4;
    size_t pr = ((size_t)b * cNP + p) * cK + lane;
    size_t cr = ((size_t)b * cNC1 + c) * cK + lane;
    float num = A * (EpL[pr] + ofE[cr]) + Cc * (GnL[pr] + ofG[cr]);
    float den = A * (eps_l[(size_t)b * cNP + p] + ofEs[b * cNC1 + c])
              + Cc * (gns_l[(size_t)b * cNP + p] + ofGs[b * cNC1 + c]);
    out[(size_t)r * cK + lane] = num / den + bias[lane];
}

// ---------------------------------------------------------------------------
extern "C" void kernel_launch(void* const* d_in, const int* in_sizes, int n_in,
                              void* d_out, int out_size, void* d_ws, size_t ws_size,
                              hipStream_t stream)
{
    const float* x    = (const float*)d_in[0];
    const float* Wa   = (const float*)d_in[1];
    const float* Wb   = (const float*)d_in[2];
    const float* wbb  = (const float*)d_in[3];
    const float* Wc   = (const float*)d_in[4];
    const float* wcb  = (const float*)d_in[5];
    const float* bias = (const float*)d_in[6];
    float* out = (float*)d_out;

    float* ws = (float*)d_ws;
    float* h     = ws + OFF_H;
    float* t1    = ws + OFF_T1;
    float* t2    = ws + OFF_T2;
    float* t2s   = ws + OFF_T2S;
    int*   idxs  = (int*)(ws + OFF_IDX);
    int*   pidx  = (int*)(ws + OFF_P);
    float* EpL   = ws + OFF_EPL;
    float* GnL   = ws + OFF_GNL;
    float* eps_l = ws + OFF_EPS;
    float* gns_l = ws + OFF_GNS;
    float* chE   = ws + OFF_CHE;
    float* chG   = ws + OFF_CHG;
    float* chEs  = ws + OFF_CHES;
    float* chGs  = ws + OFF_CHGS;
    float* ofE   = ws + OFF_OFE;
    float* ofG   = ws + OFF_OFG;
    float* ofEs  = ws + OFF_OFES;
    float* ofGs  = ws + OFF_OFGS;
    u16*   wab16 = (u16*)(ws + OFF_WB16);

    static int use_big_lds = -1;
    if (use_big_lds < 0) {
        hipError_t e = hipFuncSetAttribute((const void*)k_outf,
            hipFuncAttributeMaxDynamicSharedMemorySize, (int)SMEM_OUT);
        use_big_lds = (e == hipSuccess) ? 1 : 0;
    }

    k_prep<<<544, 256, 0, stream>>>(x, Wa, Wb, wbb, Wc, wcb, wab16, t1, t2);
    k_projrank<<<512, 256, 0, stream>>>(x, wab16, t1, t2, h, t2s, idxs, pidx);
    k_chunkscan<<<cB * cNC * 2, 64, 0, stream>>>(t2s, idxs, h, EpL, GnL, eps_l, gns_l,
                                                 chE, chG, chEs, chGs);
    if (use_big_lds) {
        k_outf<<<256, 256, SMEM_OUT, stream>>>(t1, t2s, pidx, EpL, GnL, eps_l, gns_l,
                                               chE, chG, chEs, chGs, bias, out);
    } else {
        k_offsets<<<cB * 2, 1024, 0, stream>>>(chE, chG, chEs, chGs, ofE, ofG, ofEs, ofGs);
        k_out<<<cNB / 4, 256, 0, stream>>>(t1, t2s, pidx, EpL, GnL, eps_l, gns_l,
                                           ofE, ofG, ofEs, ofGs, bias, out);
    }
}

// Round 6
// 126.436 us; speedup vs baseline: 3.2739x; 1.0019x over previous
//
#include <hip/hip_runtime.h>
#include <hip/hip_bf16.h>

// Problem constants
constexpr int cB = 4;
constexpr int cN = 4096;
constexpr int cD = 512;
constexpr int cK = 64;
constexpr int cNB = cB * cN;       // 16384 rows
constexpr int cNP = cN + 1;        // 4097 prefix rows
constexpr int cCS = 16;            // chunk size for scans
constexpr int cNC = cN / cCS;      // 256 chunks per batch
constexpr int cNC1 = cNC + 1;      // 257

typedef unsigned short u16;
typedef unsigned int u32;
typedef unsigned long long u64;
typedef __bf16 bf16x8 __attribute__((ext_vector_type(8)));
typedef float f32x4 __attribute__((ext_vector_type(4)));

// ---- workspace layout (in floats) ----
constexpr size_t OFF_H    = 0;                                  // cNB*cK
constexpr size_t OFF_T1   = OFF_H    + (size_t)cNB * cK;        // cNB
constexpr size_t OFF_T2   = OFF_T1   + cNB;                     // cNB
constexpr size_t OFF_T2S  = OFF_T2   + cNB;                     // cNB (sorted)
constexpr size_t OFF_IDX  = OFF_T2S  + cNB;                     // cNB (int)
constexpr size_t OFF_P    = OFF_IDX  + cNB;                     // cNB (int) split point per row
constexpr size_t OFF_EPL  = OFF_P    + cNB;                     // cB*cNP*cK
constexpr size_t OFF_GNL  = OFF_EPL  + (size_t)cB * cNP * cK;   // cB*cNP*cK
constexpr size_t OFF_EPS  = OFF_GNL  + (size_t)cB * cNP * cK;   // cB*cNP
constexpr size_t OFF_GNS  = OFF_EPS  + (size_t)cB * cNP;        // cB*cNP
constexpr size_t OFF_CHE  = OFF_GNS  + (size_t)cB * cNP;        // cB*cNC*cK
constexpr size_t OFF_CHG  = OFF_CHE  + (size_t)cB * cNC * cK;
constexpr size_t OFF_CHES = OFF_CHG  + (size_t)cB * cNC * cK;   // cB*cNC
constexpr size_t OFF_CHGS = OFF_CHES + (size_t)cB * cNC;
constexpr size_t OFF_OFE  = OFF_CHGS + (size_t)cB * cNC;        // cB*cNC1*cK (fallback only)
constexpr size_t OFF_OFG  = OFF_OFE  + (size_t)cB * cNC1 * cK;
constexpr size_t OFF_OFES = OFF_OFG  + (size_t)cB * cNC1 * cK;  // cB*cNC1
constexpr size_t OFF_OFGS = OFF_OFES + (size_t)cB * cNC1;
constexpr size_t OFF_WB16 = OFF_OFGS + (size_t)cB * cNC1;       // cK*cD u16

__device__ __forceinline__ u16 f2bf(float f) {
    unsigned u = __float_as_uint(f);
    u += 0x7fffu + ((u >> 16) & 1u);   // RNE
    return (u16)(u >> 16);
}
__device__ __forceinline__ u32 pk2(float a, float b) {
    return (u32)f2bf(a) | ((u32)f2bf(b) << 16);
}
// monotone float -> sortable uint (ascending)
__device__ __forceinline__ u32 f2sort(float f) {
    u32 b = __float_as_uint(f);
    u32 mask = (u32)((int)b >> 31);
    return b ^ (mask | 0x80000000u);
}

// ---------------------------------------------------------------------------
// k_prep (544 blocks): blocks <512: one pass over x -> exact f32 t1/t2 via
// in-block fold of Wa with Wb/Wc. Blocks >=512: Wa -> wab16 (bf16 B operand).
// ---------------------------------------------------------------------------
__global__ __launch_bounds__(256) void k_prep(
    const float* __restrict__ x, const float* __restrict__ Wa,
    const float* __restrict__ Wb, const float* __restrict__ wbb,
    const float* __restrict__ Wc, const float* __restrict__ wcb,
    u16* __restrict__ wab16, float* __restrict__ t1, float* __restrict__ t2)
{
    __shared__ float wabL[cD], wacL[cD];
    int t = threadIdx.x;
    if (blockIdx.x >= 512) {           // wprep slice: 32 blocks x 256 x 4 elems
        int i4 = (((int)blockIdx.x - 512) * 256 + t) * 4;
        float4 v = *(const float4*)(Wa + i4);
        uint2 p = {pk2(v.x, v.y), pk2(v.z, v.w)};
        *(uint2*)(wab16 + i4) = p;
        return;
    }
    float s1a = 0.f, s2a = 0.f, s1b = 0.f, s2b = 0.f;
#pragma unroll 8
    for (int k = 0; k < cK; ++k) {
        float wbk = Wb[k], wck = Wc[k];
        float wa1 = Wa[k * cD + t];
        float wa2 = Wa[k * cD + t + 256];
        s1a += wa1 * wbk; s2a += wa1 * wck;
        s1b += wa2 * wbk; s2b += wa2 * wck;
    }
    wabL[t] = s1a; wacL[t] = s2a; wabL[t + 256] = s1b; wacL[t + 256] = s2b;
    __syncthreads();

    int w = t >> 6, lane = t & 63;
    int d1 = lane * 4, d2 = 256 + lane * 4;
    float4 wbA = *(const float4*)&wabL[d1], wbB = *(const float4*)&wabL[d2];
    float4 wcA = *(const float4*)&wacL[d1], wcB = *(const float4*)&wacL[d2];
    float wbbv = wbb[0], wcbv = wcb[0];
#pragma unroll 2
    for (int rr = 0; rr < 8; ++rr) {
        int row = blockIdx.x * 32 + w * 8 + rr;
        const float* xp = x + (size_t)row * cD;
        float4 a  = *(const float4*)(xp + d1);
        float4 bq = *(const float4*)(xp + d2);
        float p1 = a.x*wbA.x + a.y*wbA.y + a.z*wbA.z + a.w*wbA.w
                 + bq.x*wbB.x + bq.y*wbB.y + bq.z*wbB.z + bq.w*wbB.w;
        float p2 = a.x*wcA.x + a.y*wcA.y + a.z*wcA.z + a.w*wcA.w
                 + bq.x*wcB.x + bq.y*wcB.y + bq.z*wcB.z + bq.w*wcB.w;
#pragma unroll
        for (int off = 32; off > 0; off >>= 1) {
            p1 += __shfl_down(p1, off, 64);
            p2 += __shfl_down(p2, off, 64);
        }
        if (lane == 0) { t1[row] = p1 + wbbv; t2[row] = p2 + wcbv; }
    }
}

// ---------------------------------------------------------------------------
// k_projrank (512 blocks): blocks <256 do the bf16-MFMA GEMM tile (64 rows)
// with DIRECT global->register fragments (zero LDS, zero barriers): the
// 16x16x32 A-fragment layout (lane m,quad needs x[row m][s*32+quad*8..+8])
// is natively coalesced, so staging was pure overhead. f32->bf16 RNE in
// register (bit-identical to pk2 path). B fragments from the 64 KB L1-hot
// wab16. Blocks >=256: brute-force rank with fused split-point (unchanged).
// ---------------------------------------------------------------------------
__global__ __launch_bounds__(256) void k_projrank(
    const float* __restrict__ x, const u16* __restrict__ wab16,
    const float* __restrict__ t1, const float* __restrict__ t2,
    float* __restrict__ h, float* __restrict__ t2s, int* __restrict__ idxs,
    int* __restrict__ pidx)
{
    __shared__ __align__(16) u64 shbuf[4096 + 256];   // rank: keys + part (512 ints)
    int t = threadIdx.x;
    if (blockIdx.x < 256) {
        int rowbase = blockIdx.x * 64;
        int w = t >> 6, lane = t & 63, m = lane & 15, quad = lane >> 4;
        const float* xg = x + (size_t)(rowbase + w * 16 + m) * cD + quad * 8;
        const u16* wg = wab16 + (size_t)m * cD + quad * 8;

        f32x4 acc[4] = {{0.f,0.f,0.f,0.f},{0.f,0.f,0.f,0.f},
                        {0.f,0.f,0.f,0.f},{0.f,0.f,0.f,0.f}};
#pragma unroll 4
        for (int s = 0; s < 16; ++s) {
            float4 xa  = *(const float4*)(xg + s * 32);
            float4 xb2 = *(const float4*)(xg + s * 32 + 4);
            uint4 xv = {pk2(xa.x, xa.y), pk2(xa.z, xa.w),
                        pk2(xb2.x, xb2.y), pk2(xb2.z, xb2.w)};
            bf16x8 av;
            __builtin_memcpy(&av, &xv, 16);
#pragma unroll
            for (int g = 0; g < 4; ++g) {
                uint4 wv = *(const uint4*)(wg + (size_t)g * 16 * cD + s * 32);
                bf16x8 bv;
                __builtin_memcpy(&bv, &wv, 16);
                acc[g] = __builtin_amdgcn_mfma_f32_16x16x32_bf16(av, bv, acc[g], 0, 0, 0);
            }
        }
#pragma unroll
        for (int g = 0; g < 4; ++g) {
#pragma unroll
            for (int r4 = 0; r4 < 4; ++r4) {
                int row = w * 16 + quad * 4 + r4;
                h[(size_t)(rowbase + row) * cK + g * 16 + m] = acc[g][r4];
            }
        }
    } else {
        u64* keys = shbuf;
        int* part = (int*)(shbuf + 4096);   // 512 ints
        int rb = blockIdx.x - 256;
        int b = rb >> 6;
        int rowgrp = rb & 63;
        for (int i = t; i < cN; i += 256)
            keys[i] = ((u64)f2sort(t2[b * cN + i]) << 32) | (u32)i;
        __syncthreads();
        int lane = t & 63, subset = t >> 6;
        int myrow = rowgrp * 64 + lane;
        u64 mykey = keys[myrow];
        u32 pk_hi = f2sort(-t1[(size_t)b * cN + myrow]);  // p-threshold hi word
        int s0 = subset * 1024;
        int cnt = 0, cnt2 = 0;
#pragma unroll 8
        for (int kk = 0; kk < 1024; ++kk) {
            u64 kv = keys[s0 + kk];
            cnt  += (kv < mykey) ? 1 : 0;
            cnt2 += ((u32)(kv >> 32) < pk_hi) ? 1 : 0;
        }
        part[subset * 64 + lane] = cnt;
        part[256 + subset * 64 + lane] = cnt2;
        __syncthreads();
        if (t < 64) {
            int jj = rowgrp * 64 + t;
            int rank = part[t] + part[64 + t] + part[128 + t] + part[192 + t];
            int pc   = part[256 + t] + part[320 + t] + part[384 + t] + part[448 + t];
            t2s[b * cN + rank] = t2[b * cN + jj];
            idxs[b * cN + rank] = jj;
            pidx[b * cN + jj] = pc;
        }
    }
}

// ---------------------------------------------------------------------------
// k_chunkscan: 1024 blocks x 128 thr per (batch, chunk-of-16). The 16 h-rows
// are gathered ONCE into 4 KB LDS (wave w loads rows w*8..w*8+8); wave 0
// then does the E (suffix) scan, wave 1 the G (prefix) scan. Halves the
// random-gather traffic vs the split-block version.
// ---------------------------------------------------------------------------
__global__ __launch_bounds__(128) void k_chunkscan(
    const float* __restrict__ t2s, const int* __restrict__ idxs,
    const float* __restrict__ h,
    float* __restrict__ EpL, float* __restrict__ GnL,
    float* __restrict__ eps_l, float* __restrict__ gns_l,
    float* __restrict__ chE, float* __restrict__ chG,
    float* __restrict__ chEs, float* __restrict__ chGs)
{
    __shared__ float hs[cCS][cK];      // 4 KB
    int t = threadIdx.x;
    int lane = t & 63, w = t >> 6;     // w in {0,1}
    int unit = blockIdx.x;
    int c = unit & (cNC - 1);
    int b = unit >> 8;
    int base = b * cN + c * cCS;
    size_t rowbase = ((size_t)b * cNP + c * cCS) * cK;
    int sbase = b * cNP + c * cCS;
    float M2 = t2s[b * cN + cN - 1];
    int   idxv = (lane < 8) ? idxs[base + w * 8 + lane] : 0;
    float t2v  = (lane < cCS) ? t2s[base + lane] : 0.f;

    // each wave gathers 8 h-rows into LDS
#pragma unroll
    for (int ii = 0; ii < 8; ++ii) {
        int j = __shfl(idxv, ii, 64);
        hs[w * 8 + ii][lane] = h[((size_t)b * cN + j) * cK + lane];
    }
    float slope = w ? 0.2f : 1.0f;
    float ev[cCS];
#pragma unroll
    for (int i = 0; i < cCS; ++i)
        ev[i] = __expf(slope * (__shfl(t2v, i, 64) - M2));
    __syncthreads();

    if (w == 0) {
        if (c == cNC - 1) {
            EpL[((size_t)b * cNP + cN) * cK + lane] = 0.f;
            if (lane == 0) eps_l[b * cNP + cN] = 0.f;
        }
        float acc = 0.f, accs = 0.f;
#pragma unroll
        for (int i = cCS - 1; i >= 0; --i) {
            acc += ev[i] * hs[i][lane]; accs += ev[i];
            EpL[rowbase + (size_t)i * cK + lane] = acc;
            if (lane == 0) eps_l[sbase + i] = accs;
        }
        chE[((size_t)b * cNC + c) * cK + lane] = acc;
        if (lane == 0) chEs[b * cNC + c] = accs;
    } else {
        if (c == cNC - 1) {
            GnL[((size_t)b * cNP + cN) * cK + lane] = 0.f;
            if (lane == 0) gns_l[b * cNP + cN] = 0.f;
        }
        float acc = 0.f, accs = 0.f;
#pragma unroll
        for (int i = 0; i < cCS; ++i) {
            GnL[rowbase + (size_t)i * cK + lane] = acc;
            if (lane == 0) gns_l[sbase + i] = accs;
            acc += ev[i] * hs[i][lane]; accs += ev[i];
        }
        chG[((size_t)b * cNC + c) * cK + lane] = acc;
        if (lane == 0) chGs[b * cNC + c] = accs;
    }
}

// ---------------------------------------------------------------------------
// k_outf: 256 blocks x 256 thr x 64 rows. Per-block prelude rebuilds the
// batch's offset tables in 135 KB dynamic LDS from chE/chG (replaces the
// k_offsets kernel + boundary). Main loop: 16 rows/wave, gather + combine.
// ---------------------------------------------------------------------------
constexpr unsigned SMEM_OUT = 134664;
__global__ __launch_bounds__(256, 1) void k_outf(
    const float* __restrict__ t1, const float* __restrict__ t2s,
    const int* __restrict__ pidx,
    const float* __restrict__ EpL, const float* __restrict__ GnL,
    const float* __restrict__ eps_l, const float* __restrict__ gns_l,
    const float* __restrict__ chE, const float* __restrict__ chG,
    const float* __restrict__ chEs, const float* __restrict__ chGs,
    const float* __restrict__ bias, float* __restrict__ out)
{
    extern __shared__ char sm[];
    float (*ofEl)[64] = (float(*)[64])(sm);                 // 257*64
    float (*ofGl)[64] = (float(*)[64])(sm + 65792);         // 257*64
    float* ofEsL      = (float*)(sm + 131584);              // 257
    float* ofGsL      = (float*)(sm + 132612);              // 257
    float (*wsum)[64] = (float(*)[64])(sm + 133640);        // 4*64

    int t = threadIdx.x, lane = t & 63, w = t >> 6;
    int blk = blockIdx.x;
    int b = blk >> 6;
    const float* chEb = chE + (size_t)b * cNC * cK;
    const float* chGb = chG + (size_t)b * cNC * cK;
    int c0 = w * 64;

    // ---- E suffix scan (vector) + scalar scans on waves 0/1 ----
    {
        float cv[64]; float s = 0.f;
#pragma unroll
        for (int i = 0; i < 64; ++i) { cv[i] = chEb[(size_t)(c0 + i) * cK + lane]; s += cv[i]; }
        wsum[w][lane] = s;
        if (w == 0) {
            float e0 = chEs[b*cNC + lane*4+0], e1 = chEs[b*cNC + lane*4+1];
            float e2 = chEs[b*cNC + lane*4+2], e3 = chEs[b*cNC + lane*4+3];
            float p = e0+e1+e2+e3, s2 = p;
#pragma unroll
            for (int off = 1; off < 64; off <<= 1) {
                float tv = __shfl_down(s2, off, 64);
                if (lane + off < 64) s2 += tv;
            }
            float excl = s2 - p;                  // sum over lanes > lane
            ofEsL[lane*4+0] = excl + e1 + e2 + e3;
            ofEsL[lane*4+1] = excl + e2 + e3;
            ofEsL[lane*4+2] = excl + e3;
            ofEsL[lane*4+3] = excl;
            if (lane == 0) ofEsL[cNC] = 0.f;
        } else if (w == 1) {
            float e0 = chGs[b*cNC + lane*4+0], e1 = chGs[b*cNC + lane*4+1];
            float e2 = chGs[b*cNC + lane*4+2], e3 = chGs[b*cNC + lane*4+3];
            float p = e0+e1+e2+e3, s2 = p;
#pragma unroll
            for (int off = 1; off < 64; off <<= 1) {
                float tv = __shfl_up(s2, off, 64);
                if (lane >= off) s2 += tv;
            }
            float excl = s2 - p;                  // sum over lanes < lane
            ofGsL[lane*4+0] = excl;
            ofGsL[lane*4+1] = excl + e0;
            ofGsL[lane*4+2] = excl + e0 + e1;
            ofGsL[lane*4+3] = excl + e0 + e1 + e2;
            if (lane == 63) ofGsL[cNC] = s2;
        }
        __syncthreads();
        float base = 0.f;
        for (int w2 = w + 1; w2 < 4; ++w2) base += wsum[w2][lane];
        float run = base;
#pragma unroll
        for (int i = 63; i >= 0; --i) { ofEl[c0 + i][lane] = run; run += cv[i]; }
        if (w == 0) ofEl[cNC][lane] = 0.f;
    }
    __syncthreads();    // wsum reuse guard (base reads done)
    // ---- G prefix scan (vector) ----
    {
        float cv[64]; float s = 0.f;
#pragma unroll
        for (int i = 0; i < 64; ++i) { cv[i] = chGb[(size_t)(c0 + i) * cK + lane]; s += cv[i]; }
        wsum[w][lane] = s;
        __syncthreads();
        float base = 0.f;
        for (int w2 = 0; w2 < w; ++w2) base += wsum[w2][lane];
        float run = base;
#pragma unroll
        for (int i = 0; i < 64; ++i) { ofGl[c0 + i][lane] = run; run += cv[i]; }
        if (w == 3) ofGl[cNC][lane] = run;
    }
    __syncthreads();

    // ---- main: 64 rows/block, 16 rows/wave ----
    float bv = bias[lane];
    float M2 = t2s[(size_t)b * cN + cN - 1];
    int r0 = blk * 64 + w * 16;
    const float* epsb = eps_l + (size_t)b * cNP;
    const float* gnsb = gns_l + (size_t)b * cNP;
#pragma unroll 8
    for (int i = 0; i < 16; ++i) {
        int r = r0 + i;
        float T1 = t1[r];
        float smax = T1 + M2;
        float m = fmaxf(smax, 0.2f * smax);      // leaky_relu(smax) = row max
        float A  = __expf(smax - m);
        float Cc = __expf(0.2f * smax - m);
        int p = pidx[r];
        int c = p >> 4;
        size_t pr = ((size_t)b * cNP + p) * cK + lane;
        float num = A * (EpL[pr] + ofEl[c][lane]) + Cc * (GnL[pr] + ofGl[c][lane]);
        float den = A * (epsb[p] + ofEsL[c]) + Cc * (gnsb[p] + ofGsL[c]);
        out[(size_t)r * cK + lane] = num / den + bv;
    }
}

// ---------------------------------------------------------------------------
// Fallback pair (only if the 135 KB LDS attribute is unavailable).
// ---------------------------------------------------------------------------
__global__ __launch_bounds__(1024) void k_offsets(
    const float* __restrict__ chE, const float* __restrict__ chG,
    const float* __restrict__ chEs, const float* __restrict__ chGs,
    float* __restrict__ ofE, float* __restrict__ ofG,
    float* __restrict__ ofEs, float* __restrict__ ofGs)
{
    __shared__ float wsum[16][64];
    int t = threadIdx.x;
    int lane = t & 63, w = t >> 6;
    int dir = blockIdx.x & 1;
    int b = blockIdx.x >> 1;
    const float* ch = dir ? chG : chE;
    float* of = dir ? ofG : ofE;
    int c0 = w * 16;

    float cv[16];
    float s = 0.f;
#pragma unroll
    for (int i = 0; i < 16; ++i) {
        cv[i] = ch[((size_t)b * cNC + c0 + i) * cK + lane];
        s += cv[i];
    }
    wsum[w][lane] = s;
    __syncthreads();
    float base = 0.f;
    if (dir == 0) { for (int w2 = w + 1; w2 < 16; ++w2) base += wsum[w2][lane]; }
    else          { for (int w2 = 0; w2 < w; ++w2) base += wsum[w2][lane]; }

    if (dir == 0) {
        float run = base;
#pragma unroll
        for (int i = 15; i >= 0; --i) {
            of[((size_t)b * cNC1 + c0 + i) * cK + lane] = run;
            run += cv[i];
        }
        if (w == 0) of[((size_t)b * cNC1 + cNC) * cK + lane] = 0.f;
    } else {
        float run = base;
#pragma unroll
        for (int i = 0; i < 16; ++i) {
            of[((size_t)b * cNC1 + c0 + i) * cK + lane] = run;
            run += cv[i];
        }
        if (w == 15) of[((size_t)b * cNC1 + cNC) * cK + lane] = run;
    }

    if (w == 0) {
        const float* chs = dir ? chGs : chEs;
        float* ofs = dir ? ofGs : ofEs;
        float e0 = chs[b * cNC + lane * 4 + 0];
        float e1 = chs[b * cNC + lane * 4 + 1];
        float e2 = chs[b * cNC + lane * 4 + 2];
        float e3 = chs[b * cNC + lane * 4 + 3];
        float p = e0 + e1 + e2 + e3;
        if (dir == 0) {
            float s2 = p;
#pragma unroll
            for (int off = 1; off < 64; off <<= 1) {
                float tv = __shfl_down(s2, off, 64);
                if (lane + off < 64) s2 += tv;
            }
            float excl = s2 - p;
            ofs[b * cNC1 + lane * 4 + 0] = excl + e1 + e2 + e3;
            ofs[b * cNC1 + lane * 4 + 1] = excl + e2 + e3;
            ofs[b * cNC1 + lane * 4 + 2] = excl + e3;
            ofs[b * cNC1 + lane * 4 + 3] = excl;
            if (lane == 0) ofs[b * cNC1 + cNC] = 0.f;
        } else {
            float s2 = p;
#pragma unroll
            for (int off = 1; off < 64; off <<= 1) {
                float tv = __shfl_up(s2, off, 64);
                if (lane >= off) s2 += tv;
            }
            float excl = s2 - p;
            ofs[b * cNC1 + lane * 4 + 0] = excl;
            ofs[b * cNC1 + lane * 4 + 1] = excl + e0;
            ofs[b * cNC1 + lane * 4 + 2] = excl + e0 + e1;
            ofs[b * cNC1 + lane * 4 + 3] = excl + e0 + e1 + e2;
            if (lane == 63) ofs[b * cNC1 + cNC] = s2;
        }
    }
}

__global__ __launch_bounds__(256) void k_out(
    const float* __restrict__ t1, const float* __restrict__ t2s,
    const int* __restrict__ pidx,
    const float* __restrict__ EpL, const float* __restrict__ GnL,
    const float* __restrict__ eps_l, const float* __restrict__ gns_l,
    const float* __restrict__ ofE, const float* __restrict__ ofG,
    const float* __restrict__ ofEs, const float* __restrict__ ofGs,
    const float* __restrict__ bias, float* __restrict__ out)
{
    int tid = threadIdx.x;
    int lane = tid & 63;
    int r = blockIdx.x * 4 + (tid >> 6);
    int b = r >> 12;
    float T1 = t1[r];
    float M2 = t2s[b * cN + cN - 1];
    float smax = T1 + M2;
    float m = fmaxf(smax, 0.2f * smax);
    float A  = __expf(smax - m);
    float Cc = __expf(0.2f * smax - m);
    int p = pidx[r];
    int c = p >> 4;
    size_t pr = ((size_t)b * cNP + p) * cK + lane;
    size_t cr = ((size_t)b * cNC1 + c) * cK + lane;
    float num = A * (EpL[pr] + ofE[cr]) + Cc * (GnL[pr] + ofG[cr]);
    float den = A * (eps_l[(size_t)b * cNP + p] + ofEs[b * cNC1 + c])
              + Cc * (gns_l[(size_t)b * cNP + p] + ofGs[b * cNC1 + c]);
    out[(size_t)r * cK + lane] = num / den + bias[lane];
}

// ---------------------------------------------------------------------------
extern "C" void kernel_launch(void* const* d_in, const int* in_sizes, int n_in,
                              void* d_out, int out_size, void* d_ws, size_t ws_size,
                              hipStream_t stream)
{
    const float* x    = (const float*)d_in[0];
    const float* Wa   = (const float*)d_in[1];
    const float* Wb   = (const float*)d_in[2];
    const float* wbb  = (const float*)d_in[3];
    const float* Wc   = (const float*)d_in[4];
    const float* wcb  = (const float*)d_in[5];
    const float* bias = (const float*)d_in[6];
    float* out = (float*)d_out;

    float* ws = (float*)d_ws;
    float* h     = ws + OFF_H;
    float* t1    = ws + OFF_T1;
    float* t2    = ws + OFF_T2;
    float* t2s   = ws + OFF_T2S;
    int*   idxs  = (int*)(ws + OFF_IDX);
    int*   pidx  = (int*)(ws + OFF_P);
    float* EpL   = ws + OFF_EPL;
    float* GnL   = ws + OFF_GNL;
    float* eps_l = ws + OFF_EPS;
    float* gns_l = ws + OFF_GNS;
    float* chE   = ws + OFF_CHE;
    float* chG   = ws + OFF_CHG;
    float* chEs  = ws + OFF_CHES;
    float* chGs  = ws + OFF_CHGS;
    float* ofE   = ws + OFF_OFE;
    float* ofG   = ws + OFF_OFG;
    float* ofEs  = ws + OFF_OFES;
    float* ofGs  = ws + OFF_OFGS;
    u16*   wab16 = (u16*)(ws + OFF_WB16);

    static int use_big_lds = -1;
    if (use_big_lds < 0) {
        hipError_t e = hipFuncSetAttribute((const void*)k_outf,
            hipFuncAttributeMaxDynamicSharedMemorySize, (int)SMEM_OUT);
        use_big_lds = (e == hipSuccess) ? 1 : 0;
    }

    k_prep<<<544, 256, 0, stream>>>(x, Wa, Wb, wbb, Wc, wcb, wab16, t1, t2);
    k_projrank<<<512, 256, 0, stream>>>(x, wab16, t1, t2, h, t2s, idxs, pidx);
    k_chunkscan<<<cB * cNC, 128, 0, stream>>>(t2s, idxs, h, EpL, GnL, eps_l, gns_l,
                                              chE, chG, chEs, chGs);
    if (use_big_lds) {
        k_outf<<<256, 256, SMEM_OUT, stream>>>(t1, t2s, pidx, EpL, GnL, eps_l, gns_l,
                                               chE, chG, chEs, chGs, bias, out);
    } else {
        k_offsets<<<cB * 2, 1024, 0, stream>>>(chE, chG, chEs, chGs, ofE, ofG, ofEs, ofGs);
        k_out<<<cNB / 4, 256, 0, stream>>>(t1, t2s, pidx, EpL, GnL, eps_l, gns_l,
                                           ofE, ofG, ofEs, ofGs, bias, out);
    }
}